// Round 3
// baseline (422.284 us; speedup 1.0000x reference)
//
#include <hip/hip_runtime.h>
#include <float.h>

// Problem constants (from reference)
#define NBX 512
#define NBY 512
#define NBINS (NBX * NBY)

// ==================== v3: 16K-key sort + register gather ====================
#define KEYS 16384            // 32 y-strips (by0>>4) x 512 kx
#define CHUNK 8192
#define CBLK 256

// K1: per-chunk 16K-key histogram (keys: rgy*512 + kx)
__global__ void count16k_kernel(const float* __restrict__ pos,
                                const float* __restrict__ nsx_,
                                const float* __restrict__ nsy_,
                                unsigned short* __restrict__ cnt, int n) {
    __shared__ unsigned int lh[KEYS];  // 64 KB
    int b = blockIdx.x, tid = threadIdx.x;
    for (int k = tid; k < KEYS; k += CBLK) lh[k] = 0;
    __syncthreads();
    int start = b * CHUNK;
    for (int it = 0; it < CHUNK / CBLK; ++it) {
        int i = start + it * CBLK + tid;
        if (i < n) {
            float cx = pos[i] + 0.5f * nsx_[i];
            float cy = pos[i + n] + 0.5f * nsy_[i];
            int kx = (int)floorf(cx - 1.0f);
            kx = min(max(kx, 0), NBX - 1);
            int by0 = (int)floorf(cy - 1.0f);
            int rgy = min(max(by0, 0), NBY - 1) >> 4;
            atomicAdd(&lh[rgy * NBX + kx], 1u);
        }
    }
    __syncthreads();
    for (int k = tid; k < KEYS; k += CBLK)
        cnt[(size_t)b * KEYS + k] = (unsigned short)lh[k];
}

// K2: per-key exclusive scan over chunks (thread per key)
__global__ void scan_chunks16k_kernel(const unsigned short* __restrict__ cnt,
                                      unsigned short* __restrict__ rowoff,
                                      unsigned int* __restrict__ totals, int nchunk) {
    int key = blockIdx.x * 64 + threadIdx.x;
    unsigned int run = 0;
    for (int c = 0; c < nchunk; ++c) {
        unsigned short v = cnt[(size_t)c * KEYS + key];
        rowoff[(size_t)c * KEYS + key] = (unsigned short)run;
        run += v;
    }
    totals[key] = run;
}

// K3: exclusive scan of 16384 totals -> base[KEYS+1]
__global__ void scan_totals16k_kernel(const unsigned int* __restrict__ totals,
                                      unsigned int* __restrict__ base) {
    __shared__ unsigned int bsum[1024];
    int t = threadIdx.x;
    unsigned int loc[16];
    unsigned int s_ = 0;
#pragma unroll
    for (int j = 0; j < 16; ++j) { loc[j] = totals[t * 16 + j]; s_ += loc[j]; }
    bsum[t] = s_;
    __syncthreads();
    for (int d = 1; d < 1024; d <<= 1) {
        unsigned int v = (t >= d) ? bsum[t - d] : 0;
        __syncthreads();
        bsum[t] += v;
        __syncthreads();
    }
    unsigned int run = bsum[t] - s_;  // exclusive prefix of this thread's group
#pragma unroll
    for (int j = 0; j < 16; ++j) { base[t * 16 + j] = run; run += loc[j]; }
    if (t == 1023) base[KEYS] = run;
}

// K4: key-sorted payload scatter (LDS cursors only)
__global__ void scatter16k_kernel(const float* __restrict__ pos,
                                  const float* __restrict__ nsx_,
                                  const float* __restrict__ nsy_,
                                  const unsigned int* __restrict__ base,
                                  const unsigned short* __restrict__ rowoff,
                                  float4* __restrict__ payload, int n) {
    __shared__ unsigned int lcur[KEYS];  // 64 KB
    int b = blockIdx.x, tid = threadIdx.x;
    for (int k = tid; k < KEYS; k += CBLK)
        lcur[k] = base[k] + (unsigned int)rowoff[(size_t)b * KEYS + k];
    __syncthreads();
    int start = b * CHUNK;
    for (int it = 0; it < CHUNK / CBLK; ++it) {
        int i = start + it * CBLK + tid;
        if (i < n) {
            float nx = nsx_[i], ny = nsy_[i];
            float cx = pos[i] + 0.5f * nx;
            float cy = pos[i + n] + 0.5f * ny;
            float sc = 0.25f * nx * ny;  // /(sx*sy), sx=sy=1 exactly (ns<=1)
            int kx = (int)floorf(cx - 1.0f);
            kx = min(max(kx, 0), NBX - 1);
            int by0 = (int)floorf(cy - 1.0f);
            int rgy = min(max(by0, 0), NBY - 1) >> 4;
            unsigned int p = atomicAdd(&lcur[rgy * NBX + kx], 1u);
            payload[p] = make_float4(cx, cy, sc, 0.0f);
        }
    }
}

// K5: register gather. Grid 512 = 16 x-tiles(32 cols) x 32 strips.
// Thread: (s split, gxl 0..31, yq 0..3) -> bin column gx, 4 y-bins; acc in regs.
__global__ void gather16k_kernel(const float4* __restrict__ payload,
                                 const unsigned int* __restrict__ base,
                                 const float* __restrict__ init_map,
                                 float* __restrict__ psum,
                                 float* __restrict__ pmax) {
    __shared__ float tile[32][16];
    __shared__ float rs[256];
    __shared__ float rm[256];
    int bid = blockIdx.x;
    int tx = bid & 15, rgy = bid >> 4;
    int gx0 = tx * 32;
    int tid = threadIdx.x;
    int s = tid >> 7;          // split 0/1
    int r = tid & 127;
    int gxl = r >> 2;          // 0..31
    int yq = r & 3;            // y quarter
    int gx = gx0 + gxl;
    int ybase = rgy * 16 + yq * 4;
    float gxf = (float)gx;
    float acc0 = 0.f, acc1 = 0.f, acc2 = 0.f, acc3 = 0.f;

    for (int pass = 0; pass < 2; ++pass) {
        int srow = rgy - pass;
        if (srow < 0) continue;
        if (pass == 1 && yq != 0) continue;  // only boundary rows need strip below
        for (int dx = -2; dx <= 0; ++dx) {
            int kx = gx + dx;
            if (kx < 0) continue;
            int key = srow * NBX + kx;
            unsigned int b0 = base[key], b1 = base[key + 1];
            int len = (int)(b1 - b0);
            int j0 = (int)b0 + ((len * s) >> 1);
            int j1 = (int)b0 + ((len * (s + 1)) >> 1);
            for (int j = j0; j < j1; ++j) {
                float4 p = payload[j];
                float ovx = fminf(p.x + 1.0f, gxf + 1.0f) - fmaxf(p.x - 1.0f, gxf);
                ovx = fmaxf(ovx, 0.0f);
                float sox = p.z * ovx;
                float cym1 = p.y - 1.0f;
                float by0f = floorf(cym1);
                float f = cym1 - by0f;      // exact; weights (1-f, 1, f)
                int b0l = (int)by0f - ybase;
                {
                    int d = 0 - b0l;
                    float w = (d == 0) ? (1.0f - f) : ((d == 1) ? 1.0f : ((d == 2) ? f : 0.0f));
                    acc0 = fmaf(sox, w, acc0);
                }
                {
                    int d = 1 - b0l;
                    float w = (d == 0) ? (1.0f - f) : ((d == 1) ? 1.0f : ((d == 2) ? f : 0.0f));
                    acc1 = fmaf(sox, w, acc1);
                }
                {
                    int d = 2 - b0l;
                    float w = (d == 0) ? (1.0f - f) : ((d == 1) ? 1.0f : ((d == 2) ? f : 0.0f));
                    acc2 = fmaf(sox, w, acc2);
                }
                {
                    int d = 3 - b0l;
                    float w = (d == 0) ? (1.0f - f) : ((d == 1) ? 1.0f : ((d == 2) ? f : 0.0f));
                    acc3 = fmaf(sox, w, acc3);
                }
            }
        }
    }

    // combine split s=0 / s=1 via LDS (no atomics: unique cells per phase)
    if (s == 0) {
        tile[gxl][yq * 4 + 0] = acc0;
        tile[gxl][yq * 4 + 1] = acc1;
        tile[gxl][yq * 4 + 2] = acc2;
        tile[gxl][yq * 4 + 3] = acc3;
    }
    __syncthreads();
    if (s == 1) {
        tile[gxl][yq * 4 + 0] += acc0;
        tile[gxl][yq * 4 + 1] += acc1;
        tile[gxl][yq * 4 + 2] += acc2;
        tile[gxl][yq * 4 + 3] += acc3;
    }
    __syncthreads();

    // init_map add + fused overflow/max over this 32x16 tile
    float osum = 0.0f, omax = -FLT_MAX;
    for (int c = tid; c < 512; c += 256) {
        int cxl = c >> 4, cyl = c & 15;
        float v = tile[cxl][cyl] +
                  init_map[(size_t)(gx0 + cxl) * NBY + rgy * 16 + cyl];
        osum += fmaxf(v - 1.0f, 0.0f);
        omax = fmaxf(omax, v);
    }
    rs[tid] = osum;
    rm[tid] = omax;
    __syncthreads();
    for (int off = 128; off > 0; off >>= 1) {
        if (tid < off) {
            rs[tid] += rs[tid + off];
            rm[tid] = fmaxf(rm[tid], rm[tid + off]);
        }
        __syncthreads();
    }
    if (tid == 0) { psum[bid] = rs[0]; pmax[bid] = rm[0]; }
}

__global__ void final512_kernel(const float* __restrict__ psum,
                                const float* __restrict__ pmax,
                                float* __restrict__ out) {
    __shared__ float rs[512];
    __shared__ float rm[512];
    int t = threadIdx.x;
    rs[t] = psum[t];
    rm[t] = pmax[t];
    __syncthreads();
    for (int off = 256; off > 0; off >>= 1) {
        if (t < off) {
            rs[t] += rs[t + off];
            rm[t] = fmaxf(rm[t], rm[t + off]);
        }
        __syncthreads();
    }
    if (t == 0) { out[0] = rs[0]; out[1] = rm[0]; }
}

// ==================== r2 fallback (region sort + LDS-atomic tiles) =========
#define RGB 16
#define NREG 1024
#define TILE_W 18
#define TILE_ELEMS (TILE_W * TILE_W)
#define RBLOCKS 256
#define RTHREADS 256

__device__ __forceinline__ int node_region(const float* __restrict__ pos,
                                           const float* __restrict__ nsx_,
                                           const float* __restrict__ nsy_,
                                           int i, int n,
                                           float& cx, float& cy, float& sc) {
    float x = pos[i];
    float y = pos[i + n];
    float nx = nsx_[i];
    float ny = nsy_[i];
    cx = x + 0.5f * nx;
    cy = y + 0.5f * ny;
    sc = 0.25f * nx * ny;
    int bx0 = (int)floorf(cx - 1.0f);
    int by0 = (int)floorf(cy - 1.0f);
    int rgx = min(max(bx0, 0), NBX - 1) >> 4;
    int rgy = min(max(by0, 0), NBY - 1) >> 4;
    return (rgx << 5) | rgy;
}

__global__ void count_kernel(const float* __restrict__ pos,
                             const float* __restrict__ nsx_,
                             const float* __restrict__ nsy_,
                             int* __restrict__ cnt, int n) {
    __shared__ int lhist[NREG];
    int b = blockIdx.x, tid = threadIdx.x;
    for (int r = tid; r < NREG; r += CBLK) lhist[r] = 0;
    __syncthreads();
    int start = b * CHUNK;
    for (int it = 0; it < CHUNK / CBLK; ++it) {
        int i = start + it * CBLK + tid;
        if (i < n) {
            float cx, cy, sc;
            int r = node_region(pos, nsx_, nsy_, i, n, cx, cy, sc);
            atomicAdd(&lhist[r], 1);
        }
    }
    __syncthreads();
    for (int r = tid; r < NREG; r += CBLK) cnt[b * NREG + r] = lhist[r];
}

__global__ void scan_chunks_kernel(const int* __restrict__ cnt,
                                   int* __restrict__ rowoff,
                                   int* __restrict__ totals, int nchunk) {
    int r = blockIdx.x;
    int lane = threadIdx.x;
    int running = 0;
    for (int seg = 0; seg < nchunk; seg += 64) {
        int b = seg + lane;
        int c = (b < nchunk) ? cnt[b * NREG + r] : 0;
        int inc = c;
        for (int d = 1; d < 64; d <<= 1) {
            int v = __shfl_up(inc, d, 64);
            if (lane >= d) inc += v;
        }
        if (b < nchunk) rowoff[b * NREG + r] = running + (inc - c);
        running += __shfl(inc, 63, 64);
    }
    if (lane == 0) totals[r] = running;
}

__global__ void scan_totals_kernel(const int* __restrict__ totals,
                                   int* __restrict__ base) {
    __shared__ int buf[NREG];
    int t = threadIdx.x;
    int my = totals[t];
    buf[t] = my;
    __syncthreads();
    for (int d = 1; d < NREG; d <<= 1) {
        int v = (t >= d) ? buf[t - d] : 0;
        __syncthreads();
        buf[t] += v;
        __syncthreads();
    }
    base[t] = buf[t] - my;
}

__global__ void scatter_sort_kernel(const float* __restrict__ pos,
                                    const float* __restrict__ nsx_,
                                    const float* __restrict__ nsy_,
                                    const int* __restrict__ base,
                                    const int* __restrict__ rowoff,
                                    float* __restrict__ payload, int n) {
    __shared__ int lcur[NREG];
    int b = blockIdx.x, tid = threadIdx.x;
    for (int r = tid; r < NREG; r += CBLK)
        lcur[r] = base[r] + rowoff[b * NREG + r];
    __syncthreads();
    int start = b * CHUNK;
    for (int it = 0; it < CHUNK / CBLK; ++it) {
        int i = start + it * CBLK + tid;
        if (i < n) {
            float cx, cy, sc;
            int r = node_region(pos, nsx_, nsy_, i, n, cx, cy, sc);
            int p = atomicAdd(&lcur[r], 1);
            payload[3 * p] = cx;
            payload[3 * p + 1] = cy;
            payload[3 * p + 2] = sc;
        }
    }
}

__global__ void accumulate_kernel(const float* __restrict__ payload,
                                  const int* __restrict__ base,
                                  const int* __restrict__ totals,
                                  float* __restrict__ tiles) {
    __shared__ float tile[TILE_ELEMS];
    int r = blockIdx.x, tid = threadIdx.x;
    for (int j = tid; j < TILE_ELEMS; j += 256) tile[j] = 0.0f;
    __syncthreads();
    int s = base[r];
    int e = s + totals[r];
    int ox = (r >> 5) * RGB;
    int oy = (r & 31) * RGB;
    for (int i = s + tid; i < e; i += 256) {
        float cx = payload[3 * i];
        float cy = payload[3 * i + 1];
        float sc = payload[3 * i + 2];
        int bx0 = (int)floorf(cx - 1.0f);
        int by0 = (int)floorf(cy - 1.0f);
        float ovx[3], ovy[3];
        bool okx[3], oky[3];
#pragma unroll
        for (int k = 0; k < 3; ++k) {
            int bi = bx0 + k;
            float bl = (float)bi;
            float o = fminf(cx + 1.0f, bl + 1.0f) - fmaxf(cx - 1.0f, bl);
            ovx[k] = fmaxf(o, 0.0f);
            okx[k] = (bi >= 0) && (bi < NBX);
            bi = by0 + k;
            bl = (float)bi;
            o = fminf(cy + 1.0f, bl + 1.0f) - fmaxf(cy - 1.0f, bl);
            ovy[k] = fmaxf(o, 0.0f);
            oky[k] = (bi >= 0) && (bi < NBY);
        }
#pragma unroll
        for (int kx = 0; kx < 3; ++kx) {
            if (!okx[kx]) continue;
            float sox = sc * ovx[kx];
            int rowb = (bx0 + kx - ox) * TILE_W - oy;
#pragma unroll
            for (int ky = 0; ky < 3; ++ky) {
                if (oky[ky]) atomicAdd(&tile[rowb + by0 + ky], sox * ovy[ky]);
            }
        }
    }
    __syncthreads();
    for (int j = tid; j < TILE_ELEMS; j += 256) tiles[r * TILE_ELEMS + j] = tile[j];
}

__global__ void gather_reduce_kernel(const float* __restrict__ tiles,
                                     const float* __restrict__ init_map,
                                     float* __restrict__ psum,
                                     float* __restrict__ pmax) {
    __shared__ float ssum[RTHREADS];
    __shared__ float smax[RTHREADS];
    float s = 0.0f;
    float m = -FLT_MAX;
    for (int i = blockIdx.x * blockDim.x + threadIdx.x; i < NBINS;
         i += gridDim.x * blockDim.x) {
        int gx = i >> 9;
        int gy = i & (NBY - 1);
        float v = init_map[i];
        int rx1 = gx >> 4, ry1 = gy >> 4;
#pragma unroll
        for (int dx = 0; dx < 2; ++dx) {
            int rx = rx1 - dx;
            if (rx < 0) continue;
            int tix = gx - rx * RGB;
            if (tix >= TILE_W) continue;
#pragma unroll
            for (int dy = 0; dy < 2; ++dy) {
                int ry = ry1 - dy;
                if (ry < 0) continue;
                int tiy = gy - ry * RGB;
                if (tiy >= TILE_W) continue;
                v += tiles[((rx << 5) | ry) * TILE_ELEMS + tix * TILE_W + tiy];
            }
        }
        s += fmaxf(v - 1.0f, 0.0f);
        m = fmaxf(m, v);
    }
    ssum[threadIdx.x] = s;
    smax[threadIdx.x] = m;
    __syncthreads();
    for (int off = RTHREADS / 2; off > 0; off >>= 1) {
        if (threadIdx.x < off) {
            ssum[threadIdx.x] += ssum[threadIdx.x + off];
            smax[threadIdx.x] = fmaxf(smax[threadIdx.x], smax[threadIdx.x + off]);
        }
        __syncthreads();
    }
    if (threadIdx.x == 0) {
        psum[blockIdx.x] = ssum[0];
        pmax[blockIdx.x] = smax[0];
    }
}

__global__ void final_reduce_kernel(const float* __restrict__ psum,
                                    const float* __restrict__ pmax,
                                    float* __restrict__ out) {
    __shared__ float ssum[RBLOCKS];
    __shared__ float smax[RBLOCKS];
    int t = threadIdx.x;
    ssum[t] = psum[t];
    smax[t] = pmax[t];
    __syncthreads();
    for (int off = RBLOCKS / 2; off > 0; off >>= 1) {
        if (t < off) {
            ssum[t] += ssum[t + off];
            smax[t] = fmaxf(smax[t], smax[t + off]);
        }
        __syncthreads();
    }
    if (t == 0) {
        out[0] = ssum[0];
        out[1] = smax[0];
    }
}
// ===========================================================================

extern "C" void kernel_launch(void* const* d_in, const int* in_sizes, int n_in,
                              void* d_out, int out_size, void* d_ws, size_t ws_size,
                              hipStream_t stream) {
    const float* pos = (const float*)d_in[0];
    const float* ns_x = (const float*)d_in[1];
    const float* ns_y = (const float*)d_in[2];
    const float* init_map = (const float*)d_in[3];
    float* out = (float*)d_out;

    int n = in_sizes[1];
    int nchunk = (n + CHUNK - 1) / CHUNK;
    char* ws = (char*)d_ws;

    // ---- v3 layout
    size_t off = 0;
    auto alloc = [&](size_t bytes) {
        size_t cur = off;
        off += (bytes + 255) & ~(size_t)255;
        return cur;
    };
    size_t o_payload = alloc((size_t)n * 16);
    size_t o_cnt = alloc((size_t)nchunk * KEYS * 2);
    size_t o_rowoff = alloc((size_t)nchunk * KEYS * 2);
    size_t o_totals = alloc((size_t)KEYS * 4);
    size_t o_base = alloc((size_t)(KEYS + 1) * 4);
    size_t o_psum = alloc(512 * 4);
    size_t o_pmax = alloc(512 * 4);
    size_t need_v3 = off;

    if (ws_size >= need_v3) {
        float4* payload = (float4*)(ws + o_payload);
        unsigned short* cnt = (unsigned short*)(ws + o_cnt);
        unsigned short* rowoff = (unsigned short*)(ws + o_rowoff);
        unsigned int* totals = (unsigned int*)(ws + o_totals);
        unsigned int* base = (unsigned int*)(ws + o_base);
        float* psum = (float*)(ws + o_psum);
        float* pmax = (float*)(ws + o_pmax);

        count16k_kernel<<<nchunk, CBLK, 0, stream>>>(pos, ns_x, ns_y, cnt, n);
        scan_chunks16k_kernel<<<KEYS / 64, 64, 0, stream>>>(cnt, rowoff, totals, nchunk);
        scan_totals16k_kernel<<<1, 1024, 0, stream>>>(totals, base);
        scatter16k_kernel<<<nchunk, CBLK, 0, stream>>>(pos, ns_x, ns_y, base, rowoff,
                                                       payload, n);
        gather16k_kernel<<<512, 256, 0, stream>>>(payload, base, init_map, psum, pmax);
        final512_kernel<<<1, 512, 0, stream>>>(psum, pmax, out);
        return;
    }

    // ---- r2 fallback layout
    off = 0;
    size_t f_cnt = alloc((size_t)nchunk * NREG * 4);
    size_t f_rowoff = alloc((size_t)nchunk * NREG * 4);
    size_t f_totals = alloc(NREG * 4);
    size_t f_base = alloc(NREG * 4);
    size_t f_tiles = alloc((size_t)NREG * TILE_ELEMS * 4);
    size_t f_payload = alloc((size_t)n * 3 * 4);
    size_t f_psum = alloc(RBLOCKS * 4);
    size_t f_pmax = alloc(RBLOCKS * 4);

    if (ws_size >= off) {
        int* cnt = (int*)(ws + f_cnt);
        int* rowoff = (int*)(ws + f_rowoff);
        int* totals = (int*)(ws + f_totals);
        int* base = (int*)(ws + f_base);
        float* tiles = (float*)(ws + f_tiles);
        float* payload = (float*)(ws + f_payload);
        float* psum = (float*)(ws + f_psum);
        float* pmax = (float*)(ws + f_pmax);

        count_kernel<<<nchunk, CBLK, 0, stream>>>(pos, ns_x, ns_y, cnt, n);
        scan_chunks_kernel<<<NREG, 64, 0, stream>>>(cnt, rowoff, totals, nchunk);
        scan_totals_kernel<<<1, NREG, 0, stream>>>(totals, base);
        scatter_sort_kernel<<<nchunk, CBLK, 0, stream>>>(pos, ns_x, ns_y, base,
                                                         rowoff, payload, n);
        accumulate_kernel<<<NREG, 256, 0, stream>>>(payload, base, totals, tiles);
        gather_reduce_kernel<<<RBLOCKS, RTHREADS, 0, stream>>>(tiles, init_map,
                                                               psum, pmax);
        final_reduce_kernel<<<1, RBLOCKS, 0, stream>>>(psum, pmax, out);
    }
}

// Round 4
// 68.462 us; speedup vs baseline: 6.1681x; 6.1681x over previous
//
#include <hip/hip_runtime.h>
#include <float.h>

// Problem constants (from reference)
#define NBX 512
#define NBY 512
#define NBINS (NBX * NBY)

// Region decomposition: 32x32 regions of 16x16 bins each.
#define NREG 1024
#define TILE_W 18                     // 16 + 2 halo cells per axis
#define TILE_ELEMS (TILE_W * TILE_W)  // 324

// Packed-tile accumulator: two overlapping u64 grids of 4x16-bit fields.
// Grid A group g covers y-cells [4g, 4g+3]; grid B covers [4g+2, 4g+5].
// Any 3-consecutive-cell triple starting at k fits one u64:
//   grid = (k>>1)&1, k2 = k - 2*grid (k2&3 in {0,1}), grp = k2>>2,
//   shift = (k2&1)*16.  NGRP=4 covers cells 0..17.
#define NGRP 4
#define TP_WORDS (2 * TILE_W * NGRP)  // 144 u64 = 1152 B
#define FSCALE 1024.0f
#define INV_FSCALE (1.0f / 1024.0f)

#define CHUNK 8192
#define CBLK 256
#define RBLOCKS 256
#define RTHREADS 256

// node sizes in [0.2,1.0] => stretched half-widths sx=sy=1.0 exactly,
// scale = 0.25*nsx*nsy, and each axis stencil = 3 bins with analytic
// weights (1-f, 1, f), f = c-1-floor(c-1).

__device__ __forceinline__ int node_region(const float* __restrict__ pos,
                                           const float* __restrict__ nsx_,
                                           const float* __restrict__ nsy_,
                                           int i, int n,
                                           float& cx, float& cy, float& sc) {
    float x = pos[i];
    float y = pos[i + n];
    float nx = nsx_[i];
    float ny = nsy_[i];
    cx = x + 0.5f * nx;
    cy = y + 0.5f * ny;
    sc = 0.25f * nx * ny;
    int bx0 = (int)floorf(cx - 1.0f);
    int by0 = (int)floorf(cy - 1.0f);
    int rgx = min(max(bx0, 0), NBX - 1) >> 4;
    int rgy = min(max(by0, 0), NBY - 1) >> 4;
    return (rgx << 5) | rgy;
}

// K1: per-chunk region histogram (LDS u32 atomics)
__global__ void count_kernel(const float* __restrict__ pos,
                             const float* __restrict__ nsx_,
                             const float* __restrict__ nsy_,
                             int* __restrict__ cnt, int n) {
    __shared__ int lhist[NREG];
    int b = blockIdx.x, tid = threadIdx.x;
    for (int r = tid; r < NREG; r += CBLK) lhist[r] = 0;
    __syncthreads();
    int start = b * CHUNK;
    for (int it = 0; it < CHUNK / CBLK; ++it) {
        int i = start + it * CBLK + tid;
        if (i < n) {
            float cx, cy, sc;
            int r = node_region(pos, nsx_, nsy_, i, n, cx, cy, sc);
            atomicAdd(&lhist[r], 1);
        }
    }
    __syncthreads();
    for (int r = tid; r < NREG; r += CBLK) cnt[b * NREG + r] = lhist[r];
}

// K2: per-region exclusive scan over chunks (one wave per region)
__global__ void scan_chunks_kernel(const int* __restrict__ cnt,
                                   int* __restrict__ rowoff,
                                   int* __restrict__ totals, int nchunk) {
    int r = blockIdx.x;
    int lane = threadIdx.x;  // 0..63
    int running = 0;
    for (int seg = 0; seg < nchunk; seg += 64) {
        int b = seg + lane;
        int c = (b < nchunk) ? cnt[b * NREG + r] : 0;
        int inc = c;
        for (int d = 1; d < 64; d <<= 1) {
            int v = __shfl_up(inc, d, 64);
            if (lane >= d) inc += v;
        }
        if (b < nchunk) rowoff[b * NREG + r] = running + (inc - c);
        running += __shfl(inc, 63, 64);
    }
    if (lane == 0) totals[r] = running;
}

// K3: exclusive scan of 1024 region totals
__global__ void scan_totals_kernel(const int* __restrict__ totals,
                                   int* __restrict__ base) {
    __shared__ int buf[NREG];
    int t = threadIdx.x;
    int my = totals[t];
    buf[t] = my;
    __syncthreads();
    for (int d = 1; d < NREG; d <<= 1) {
        int v = (t >= d) ? buf[t - d] : 0;
        __syncthreads();
        buf[t] += v;
        __syncthreads();
    }
    base[t] = buf[t] - my;  // exclusive
}

// K4: region-sorted payload scatter (float4 payload, LDS cursors)
__global__ void scatter_sort_kernel(const float* __restrict__ pos,
                                    const float* __restrict__ nsx_,
                                    const float* __restrict__ nsy_,
                                    const int* __restrict__ base,
                                    const int* __restrict__ rowoff,
                                    float4* __restrict__ payload, int n) {
    __shared__ int lcur[NREG];
    int b = blockIdx.x, tid = threadIdx.x;
    for (int r = tid; r < NREG; r += CBLK)
        lcur[r] = base[r] + rowoff[b * NREG + r];
    __syncthreads();
    int start = b * CHUNK;
    for (int it = 0; it < CHUNK / CBLK; ++it) {
        int i = start + it * CBLK + tid;
        if (i < n) {
            float cx, cy, sc;
            int r = node_region(pos, nsx_, nsy_, i, n, cx, cy, sc);
            int p = atomicAdd(&lcur[r], 1);
            payload[p] = make_float4(cx, cy, sc, 0.0f);
        }
    }
}

// K5: per-region accumulation with packed u64 fixed-point LDS atomics.
// 3 atomics per node (one per x-column) instead of 9.
__global__ void accumulate_packed_kernel(const float4* __restrict__ payload,
                                         const int* __restrict__ base,
                                         const int* __restrict__ totals,
                                         float* __restrict__ tiles) {
    __shared__ unsigned long long tp[TP_WORDS];
    int r = blockIdx.x, tid = threadIdx.x;
    for (int j = tid; j < TP_WORDS; j += 256) tp[j] = 0ull;
    __syncthreads();
    int s = base[r];
    int e = s + totals[r];
    int ox = (r >> 5) << 4;
    int oy = (r & 31) << 4;
    for (int i = s + tid; i < e; i += 256) {
        float4 p = payload[i];
        float cx = p.x, cy = p.y, sc = p.z;
        float bx0f = floorf(cx - 1.0f);
        float by0f = floorf(cy - 1.0f);
        int bx0 = (int)bx0f;
        int by0 = (int)by0f;
        float fx = cx - 1.0f - bx0f;  // in [0,1)
        float fy = cy - 1.0f - by0f;
        float wx0 = 1.0f - fx, wx1 = 1.0f, wx2 = fx;
        float wy0 = 1.0f - fy, wy1 = 1.0f, wy2 = fy;
        if (bx0 < 0) { bx0 = 0; wx0 = 1.0f; wx1 = fx; wx2 = 0.0f; }
        if (bx0 >= NBX - 2) wx2 = 0.0f;   // drop column at bin 512
        if (by0 < 0) { by0 = 0; wy0 = 1.0f; wy1 = fy; wy2 = 0.0f; }
        if (by0 >= NBY - 2) wy2 = 0.0f;   // drop row at bin 512

        int k = by0 - oy;            // 0..15
        int grid = (k >> 1) & 1;     // (k&2)>>1
        int k2 = k - (grid << 1);    // k2&3 in {0,1}
        int grp = k2 >> 2;
        int shift = (k2 & 1) << 4;   // 0 or 16

        float a0 = sc * wy0 * FSCALE;
        float a1 = sc * wy1 * FSCALE;
        float a2 = sc * wy2 * FSCALE;
        int colb = bx0 - ox;         // 0..15
        int idxb = (grid * TILE_W + colb) * NGRP + grp;

        {
            unsigned long long q0 = (unsigned int)(a0 * wx0 + 0.5f);
            unsigned long long q1 = (unsigned int)(a1 * wx0 + 0.5f);
            unsigned long long q2 = (unsigned int)(a2 * wx0 + 0.5f);
            atomicAdd(&tp[idxb],
                      (q0 << shift) | (q1 << (shift + 16)) | (q2 << (shift + 32)));
        }
        {
            unsigned long long q0 = (unsigned int)(a0 + 0.5f);  // wx1 == 1
            unsigned long long q1 = (unsigned int)(a1 + 0.5f);
            unsigned long long q2 = (unsigned int)(a2 + 0.5f);
            atomicAdd(&tp[idxb + NGRP],
                      (q0 << shift) | (q1 << (shift + 16)) | (q2 << (shift + 32)));
        }
        if (wx2 != 0.0f) {
            unsigned long long q0 = (unsigned int)(a0 * wx2 + 0.5f);
            unsigned long long q1 = (unsigned int)(a1 * wx2 + 0.5f);
            unsigned long long q2 = (unsigned int)(a2 * wx2 + 0.5f);
            atomicAdd(&tp[idxb + 2 * NGRP],
                      (q0 << shift) | (q1 << (shift + 16)) | (q2 << (shift + 32)));
        }
    }
    __syncthreads();
    // Unpack both grids to f32 tile. Cell y: grid A field y (y<=15),
    // grid B field y-2 (y>=2).
    for (int c = tid; c < TILE_ELEMS; c += 256) {
        int col = c / TILE_W;
        int y = c - col * TILE_W;
        unsigned int acc = 0;
        if (y <= 15) {
            unsigned long long a = tp[(0 * TILE_W + col) * NGRP + (y >> 2)];
            acc += (unsigned int)(a >> ((y & 3) * 16)) & 0xFFFFu;
        }
        if (y >= 2) {
            int yb = y - 2;
            unsigned long long bv = tp[(1 * TILE_W + col) * NGRP + (yb >> 2)];
            acc += (unsigned int)(bv >> ((yb & 3) * 16)) & 0xFFFFu;
        }
        tiles[r * TILE_ELEMS + c] = (float)acc * INV_FSCALE;
    }
}

// K6: gather (<=4 tiles per bin) + init map, fused overflow/max partial reduce
__global__ void gather_reduce_kernel(const float* __restrict__ tiles,
                                     const float* __restrict__ init_map,
                                     float* __restrict__ psum,
                                     float* __restrict__ pmax) {
    __shared__ float ssum[RTHREADS];
    __shared__ float smax[RTHREADS];
    float s = 0.0f;
    float m = -FLT_MAX;
    for (int i = blockIdx.x * blockDim.x + threadIdx.x; i < NBINS;
         i += gridDim.x * blockDim.x) {
        int gx = i >> 9;
        int gy = i & (NBY - 1);
        float v = init_map[i];
        int rx1 = gx >> 4, ry1 = gy >> 4;
#pragma unroll
        for (int dx = 0; dx < 2; ++dx) {
            int rx = rx1 - dx;
            if (rx < 0) continue;
            int tix = gx - rx * 16;
            if (tix >= TILE_W) continue;
#pragma unroll
            for (int dy = 0; dy < 2; ++dy) {
                int ry = ry1 - dy;
                if (ry < 0) continue;
                int tiy = gy - ry * 16;
                if (tiy >= TILE_W) continue;
                v += tiles[((rx << 5) | ry) * TILE_ELEMS + tix * TILE_W + tiy];
            }
        }
        s += fmaxf(v - 1.0f, 0.0f);
        m = fmaxf(m, v);
    }
    ssum[threadIdx.x] = s;
    smax[threadIdx.x] = m;
    __syncthreads();
    for (int off = RTHREADS / 2; off > 0; off >>= 1) {
        if (threadIdx.x < off) {
            ssum[threadIdx.x] += ssum[threadIdx.x + off];
            smax[threadIdx.x] = fmaxf(smax[threadIdx.x], smax[threadIdx.x + off]);
        }
        __syncthreads();
    }
    if (threadIdx.x == 0) {
        psum[blockIdx.x] = ssum[0];
        pmax[blockIdx.x] = smax[0];
    }
}

__global__ void final_reduce_kernel(const float* __restrict__ psum,
                                    const float* __restrict__ pmax,
                                    float* __restrict__ out) {
    __shared__ float ssum[RBLOCKS];
    __shared__ float smax[RBLOCKS];
    int t = threadIdx.x;
    ssum[t] = psum[t];
    smax[t] = pmax[t];
    __syncthreads();
    for (int off = RBLOCKS / 2; off > 0; off >>= 1) {
        if (t < off) {
            ssum[t] += ssum[t + off];
            smax[t] = fmaxf(smax[t], smax[t + off]);
        }
        __syncthreads();
    }
    if (t == 0) {
        out[0] = ssum[0];
        out[1] = smax[0];
    }
}

// ---------- fallback path (direct global atomics), used if ws too small ----
__global__ void init_map_kernel(const float* __restrict__ init_map,
                                float* __restrict__ dm, int nbins) {
    int i = blockIdx.x * blockDim.x + threadIdx.x;
    if (i < nbins) dm[i] = init_map[i];
}

__global__ void scatter_direct_kernel(const float* __restrict__ pos,
                                      const float* __restrict__ ns_x,
                                      const float* __restrict__ ns_y,
                                      float* __restrict__ dm, int n_nodes) {
    int i = blockIdx.x * blockDim.x + threadIdx.x;
    if (i >= n_nodes) return;
    float cx, cy, sc;
    node_region(pos, ns_x, ns_y, i, n_nodes, cx, cy, sc);
    int bx0 = (int)floorf(cx - 1.0f);
    int by0 = (int)floorf(cy - 1.0f);
#pragma unroll
    for (int kx = 0; kx < 3; ++kx) {
        int bix = bx0 + kx;
        if (bix < 0 || bix >= NBX) continue;
        float bl = (float)bix;
        float ox = fmaxf(fminf(cx + 1.0f, bl + 1.0f) - fmaxf(cx - 1.0f, bl), 0.0f);
        float sox = sc * ox;
#pragma unroll
        for (int ky = 0; ky < 3; ++ky) {
            int biy = by0 + ky;
            if (biy < 0 || biy >= NBY) continue;
            bl = (float)biy;
            float oy = fmaxf(fminf(cy + 1.0f, bl + 1.0f) - fmaxf(cy - 1.0f, bl), 0.0f);
            atomicAdd(&dm[bix * NBY + biy], sox * oy);
        }
    }
}

__global__ void reduce_dm_kernel(const float* __restrict__ dm,
                                 float* __restrict__ psum,
                                 float* __restrict__ pmax, int nbins) {
    __shared__ float ssum[RTHREADS];
    __shared__ float smax[RTHREADS];
    float s = 0.0f;
    float m = -FLT_MAX;
    for (int i = blockIdx.x * blockDim.x + threadIdx.x; i < nbins;
         i += gridDim.x * blockDim.x) {
        float v = dm[i];
        s += fmaxf(v - 1.0f, 0.0f);
        m = fmaxf(m, v);
    }
    ssum[threadIdx.x] = s;
    smax[threadIdx.x] = m;
    __syncthreads();
    for (int off = RTHREADS / 2; off > 0; off >>= 1) {
        if (threadIdx.x < off) {
            ssum[threadIdx.x] += ssum[threadIdx.x + off];
            smax[threadIdx.x] = fmaxf(smax[threadIdx.x], smax[threadIdx.x + off]);
        }
        __syncthreads();
    }
    if (threadIdx.x == 0) {
        psum[blockIdx.x] = ssum[0];
        pmax[blockIdx.x] = smax[0];
    }
}
// ---------------------------------------------------------------------------

extern "C" void kernel_launch(void* const* d_in, const int* in_sizes, int n_in,
                              void* d_out, int out_size, void* d_ws, size_t ws_size,
                              hipStream_t stream) {
    const float* pos = (const float*)d_in[0];
    const float* ns_x = (const float*)d_in[1];
    const float* ns_y = (const float*)d_in[2];
    const float* init_map = (const float*)d_in[3];
    float* out = (float*)d_out;

    int n = in_sizes[1];  // node count
    int nchunk = (n + CHUNK - 1) / CHUNK;
    char* ws = (char*)d_ws;

    size_t off = 0;
    auto alloc = [&](size_t bytes) {
        size_t cur = off;
        off += (bytes + 255) & ~(size_t)255;
        return cur;
    };
    size_t o_payload = alloc((size_t)n * 16);
    size_t o_cnt = alloc((size_t)nchunk * NREG * 4);
    size_t o_rowoff = alloc((size_t)nchunk * NREG * 4);
    size_t o_totals = alloc(NREG * 4);
    size_t o_base = alloc(NREG * 4);
    size_t o_tiles = alloc((size_t)NREG * TILE_ELEMS * 4);
    size_t o_psum = alloc(RBLOCKS * 4);
    size_t o_pmax = alloc(RBLOCKS * 4);

    if (ws_size >= off) {
        float4* payload = (float4*)(ws + o_payload);
        int* cnt = (int*)(ws + o_cnt);
        int* rowoff = (int*)(ws + o_rowoff);
        int* totals = (int*)(ws + o_totals);
        int* base = (int*)(ws + o_base);
        float* tiles = (float*)(ws + o_tiles);
        float* psum = (float*)(ws + o_psum);
        float* pmax = (float*)(ws + o_pmax);

        count_kernel<<<nchunk, CBLK, 0, stream>>>(pos, ns_x, ns_y, cnt, n);
        scan_chunks_kernel<<<NREG, 64, 0, stream>>>(cnt, rowoff, totals, nchunk);
        scan_totals_kernel<<<1, NREG, 0, stream>>>(totals, base);
        scatter_sort_kernel<<<nchunk, CBLK, 0, stream>>>(pos, ns_x, ns_y, base,
                                                         rowoff, payload, n);
        accumulate_packed_kernel<<<NREG, 256, 0, stream>>>(payload, base, totals, tiles);
        gather_reduce_kernel<<<RBLOCKS, RTHREADS, 0, stream>>>(tiles, init_map,
                                                               psum, pmax);
        final_reduce_kernel<<<1, RBLOCKS, 0, stream>>>(psum, pmax, out);
    } else {
        float* dm = (float*)d_ws;
        float* psum = dm + NBINS;
        float* pmax = psum + RBLOCKS;
        init_map_kernel<<<(NBINS + 255) / 256, 256, 0, stream>>>(init_map, dm, NBINS);
        scatter_direct_kernel<<<(n + 255) / 256, 256, 0, stream>>>(pos, ns_x, ns_y, dm, n);
        reduce_dm_kernel<<<RBLOCKS, RTHREADS, 0, stream>>>(dm, psum, pmax, NBINS);
        final_reduce_kernel<<<1, RBLOCKS, 0, stream>>>(psum, pmax, out);
    }
}